// Round 1
// baseline (231.245 us; speedup 1.0000x reference)
//
#include <hip/hip_runtime.h>

#define WIDTH 1024
#define HALF  512
#define DEPTH 32
#define BATCH 32768

// Step 1: collapse the depth scan. For pair j, the difference gain is
// g_j = prod_i (1 - 2*params[j,i]); the sum is invariant.
__global__ void butterfly_gains(const float* __restrict__ params,
                                float* __restrict__ g) {
    int j = blockIdx.x * blockDim.x + threadIdx.x;
    if (j < HALF) {
        const float* p = params + (long long)j * DEPTH;
        float prod = 1.0f;
#pragma unroll
        for (int i = 0; i < DEPTH; ++i) {
            prod *= (1.0f - 2.0f * p[i]);
        }
        g[j] = prod;
    }
}

// Step 2: apply analytically, float4-vectorized.
// out0 = 0.5*(x0+x1) + 0.5*(x0-x1)*g ; out1 = 0.5*(x0+x1) - 0.5*(x0-x1)*g
__global__ void __launch_bounds__(256)
butterfly_apply(const float* __restrict__ X,
                const float* __restrict__ g,
                float* __restrict__ out) {
    const int PAIRS4 = HALF / 4;                 // 128 float4 pairs per row
    long long idx = (long long)blockIdx.x * blockDim.x + threadIdx.x;
    // idx in [0, BATCH * PAIRS4)
    int b  = (int)(idx >> 7);                    // idx / 128
    int jv = (int)(idx & 127);                   // idx % 128

    const float4* x0p = (const float4*)(X + (long long)b * WIDTH);
    const float4* x1p = (const float4*)(X + (long long)b * WIDTH + HALF);
    float4 x0 = x0p[jv];
    float4 x1 = x1p[jv];
    float4 gv = ((const float4*)g)[jv];

    float4 o0, o1;
    {
        float h = 0.5f * (x0.x + x1.x);
        float e = 0.5f * (x0.x - x1.x) * gv.x;
        o0.x = h + e; o1.x = h - e;
    }
    {
        float h = 0.5f * (x0.y + x1.y);
        float e = 0.5f * (x0.y - x1.y) * gv.y;
        o0.y = h + e; o1.y = h - e;
    }
    {
        float h = 0.5f * (x0.z + x1.z);
        float e = 0.5f * (x0.z - x1.z) * gv.z;
        o0.z = h + e; o1.z = h - e;
    }
    {
        float h = 0.5f * (x0.w + x1.w);
        float e = 0.5f * (x0.w - x1.w) * gv.w;
        o0.w = h + e; o1.w = h - e;
    }

    float4* o0p = (float4*)(out + (long long)b * WIDTH);
    float4* o1p = (float4*)(out + (long long)b * WIDTH + HALF);
    o0p[jv] = o0;
    o1p[jv] = o1;
}

extern "C" void kernel_launch(void* const* d_in, const int* in_sizes, int n_in,
                              void* d_out, int out_size, void* d_ws, size_t ws_size,
                              hipStream_t stream) {
    const float* X      = (const float*)d_in[0];
    const float* params = (const float*)d_in[1];
    float* out = (float*)d_out;
    float* g   = (float*)d_ws;   // 512 floats = 2 KB of scratch

    // Precompute per-pair difference gains (re-done every call; d_ws is
    // poisoned before each launch).
    hipLaunchKernelGGL(butterfly_gains, dim3(2), dim3(256), 0, stream, params, g);

    const long long total = (long long)BATCH * (HALF / 4);  // 4,194,304 threads
    const int threads = 256;
    const int blocks = (int)((total + threads - 1) / threads);  // 16384
    hipLaunchKernelGGL(butterfly_apply, dim3(blocks), dim3(threads), 0, stream,
                       X, g, out);
}

// Round 3
// 230.571 us; speedup vs baseline: 1.0029x; 1.0029x over previous
//
#include <hip/hip_runtime.h>

#define WIDTH  1024
#define HALF   512
#define DEPTH  32
#define BATCH  32768
#define PAIRS4 (HALF / 4)      // 128 float4 pairs per row
#define NTHREADS 256
#define NBLOCKS  2048

typedef float f4 __attribute__((ext_vector_type(4)));   // clang vector: valid for nontemporal builtins

// Depth scan collapses analytically: for pair j, sum s=x0+x1 is invariant,
// difference d=x0-x1 scales by g_j = prod_i (1 - 2*params[j,i]).
// out0 = (s + d*g)/2, out1 = (s - d*g)/2.
__global__ void __launch_bounds__(NTHREADS)
butterfly_fused(const float* __restrict__ X,
                const float* __restrict__ params,
                float* __restrict__ out) {
    __shared__ float gs[HALF];   // 2 KB

    const int tid = threadIdx.x;

    // Phase 1: per-block gain computation (params is 64 KB, L2-resident).
    for (int j = tid; j < HALF; j += NTHREADS) {
        const float* p = params + j * DEPTH;
        float prod = 1.0f;
#pragma unroll
        for (int i = 0; i < DEPTH; ++i) {
            prod *= (1.0f - 2.0f * p[i]);
        }
        gs[j] = prod;
    }
    __syncthreads();

    // Phase 2: grid-stride over all (row, float4-pair) elements.
    const long long total = (long long)BATCH * PAIRS4;   // 4,194,304
    const long long stride = (long long)NBLOCKS * NTHREADS;

    for (long long idx = (long long)blockIdx.x * NTHREADS + tid;
         idx < total; idx += stride) {
        const int b  = (int)(idx >> 7);    // row
        const int jv = (int)(idx & 127);   // float4-pair within row

        const f4* x0p = (const f4*)(X + (long long)b * WIDTH);
        const f4* x1p = x0p + PAIRS4;

        f4 x0 = __builtin_nontemporal_load(x0p + jv);
        f4 x1 = __builtin_nontemporal_load(x1p + jv);
        f4 gv = ((const f4*)gs)[jv];

        f4 h = 0.5f * (x0 + x1);
        f4 e = 0.5f * (x0 - x1) * gv;
        f4 o0 = h + e;
        f4 o1 = h - e;

        f4* o0p = (f4*)(out + (long long)b * WIDTH);
        f4* o1p = o0p + PAIRS4;
        __builtin_nontemporal_store(o0, o0p + jv);
        __builtin_nontemporal_store(o1, o1p + jv);
    }
}

extern "C" void kernel_launch(void* const* d_in, const int* in_sizes, int n_in,
                              void* d_out, int out_size, void* d_ws, size_t ws_size,
                              hipStream_t stream) {
    const float* X      = (const float*)d_in[0];
    const float* params = (const float*)d_in[1];
    float* out = (float*)d_out;

    hipLaunchKernelGGL(butterfly_fused, dim3(NBLOCKS), dim3(NTHREADS), 0, stream,
                       X, params, out);
}